// Round 14
// baseline (273.430 us; speedup 1.0000x reference)
//
#include <hip/hip_runtime.h>
#include <math.h>

#define N_NODES 100000
#define N_EDGES 1600000
#define E2 (N_EDGES + N_NODES)
#define NEG_SLOPE 0.2f

#define NPB 128                      // nodes per bucket
#define NB  ((N_NODES + NPB - 1) / NPB)   // 782 buckets
#define CAP 2600                     // per-bucket raw edge capacity (mean ~2227, +8 sigma)
#define CAPP (CAP + 3 * NPB)         // padded capacity (2984)
#define BSLACK (3 * NPB + 4)         // per-bucket slack in final CSR (388)
#define BCH 4096                     // edges per block in k_bucket (LDS-cached)

typedef unsigned int uint;
typedef unsigned short ushort;
typedef __attribute__((ext_vector_type(2))) _Float16 h2_t;
typedef __attribute__((ext_vector_type(8))) _Float16 f16x8;
typedef __attribute__((ext_vector_type(4))) float f32x4;

union U8 { uint4 q; f16x8 v; h2_t h2[4]; _Float16 h[8]; uint u[4]; };

// ---------------- fp16 helpers ----------------

__device__ inline ushort f2h(float x) {
  _Float16 h = (_Float16)x;
  return *(ushort*)&h;
}

__device__ inline float h2f(ushort u) {
  _Float16 h = *(_Float16*)&u;
  return (float)h;
}

__device__ inline h2_t pk2h(float a, float b) {
  auto r = __builtin_amdgcn_cvt_pkrtz(a, b);   // __fp16 vec2 -> bit-cast
  return *(h2_t*)&r;
}

__device__ inline float fdot2(h2_t a, h2_t b, float c) {
#if __has_builtin(__builtin_amdgcn_fdot2)
  return __builtin_amdgcn_fdot2(*(__fp16 __attribute__((ext_vector_type(2)))*)&a,
                                *(__fp16 __attribute__((ext_vector_type(2)))*)&b,
                                c, false);
#else
  return c + (float)a.x * (float)b.x + (float)a.y * (float)b.y;
#endif
}

// ---------------- prep: W transposes (fp16) + bucket cursor init ----------------

__global__ __launch_bounds__(256) void k_prepW(const float* __restrict__ W1,
                                               const float* __restrict__ W2,
                                               ushort* __restrict__ WT1,
                                               ushort* __restrict__ WT2,
                                               int* __restrict__ bcursor) {
  int b = blockIdx.x, t = threadIdx.x;
  if (b == 0) {
    for (int i = t; i < 128 * 128; i += 256) {
      int k = i >> 7, n = i & 127;
      WT1[n * 128 + k] = f2h(W1[i]);           // WT1[n][k]
    }
  } else if (b == 1) {
    for (int i = t; i < 48 * 128; i += 256) {
      int n = i >> 7, k = i & 127;
      WT2[i] = (n < 40) ? f2h(W2[k * 40 + n]) : (ushort)0;   // WT2[n][k], zero-pad n>=40
    }
  } else {
    for (int i = t; i < NB; i += 256) bcursor[i] = i * CAP;
  }
}

// ---------------- bucketed CSR construction (single global pass, LDS edge cache) ----------------

__global__ __launch_bounds__(256) void k_bucket(const int* __restrict__ ei,
                                                int* __restrict__ bcursor,
                                                uint* __restrict__ pbuf) {
  __shared__ uint pay[BCH];
  __shared__ ushort bkt[BCH];
  __shared__ int cnt[NB];
  __shared__ int base[NB];
  const int tid = threadIdx.x;
  const int ebase = blockIdx.x * BCH;
  for (int t = tid; t < NB; t += 256) cnt[t] = 0;
  __syncthreads();
#pragma unroll 4
  for (int k = 0; k < BCH / 256; ++k) {
    int idx = tid + k * 256;
    int e = ebase + idx;
    if (e < E2) {
      int s, d;
      if (e < N_EDGES) { s = ei[e]; d = ei[N_EDGES + e]; }
      else { s = e - N_EDGES; d = s; }
      pay[idx] = ((uint)s << 7) | (uint)(d & 127);
      int b = d >> 7;
      bkt[idx] = (ushort)b;
      atomicAdd(&cnt[b], 1);
    } else {
      bkt[idx] = 0xFFFFu;
    }
  }
  __syncthreads();
  for (int t = tid; t < NB; t += 256) {
    int c = cnt[t];
    base[t] = c ? atomicAdd(&bcursor[t], c) : 0;
    cnt[t] = 0;
  }
  __syncthreads();
#pragma unroll 4
  for (int k = 0; k < BCH / 256; ++k) {
    int idx = tid + k * 256;
    ushort b = bkt[idx];
    if (b != 0xFFFFu) {
      int pos = base[b] + atomicAdd(&cnt[b], 1);
      pbuf[pos] = pay[idx];
    }
  }
}

__global__ __launch_bounds__(1024) void k_scanB(const int* __restrict__ bcursor,
                                                int* __restrict__ bbase) {
  __shared__ int sm[1024];
  int t = threadIdx.x;
  int v = (t < NB) ? (bcursor[t] - t * CAP) : 0;
  sm[t] = v;
  __syncthreads();
  for (int off = 1; off < 1024; off <<= 1) {
    int u = (t >= off) ? sm[t - off] : 0;
    __syncthreads();
    sm[t] += u;
    __syncthreads();
  }
  if (t < NB) {
    int excl = sm[t] - v;
    bbase[t] = ((excl + 3) & ~3) + t * BSLACK;   // 16B-aligned start + per-bucket pad slack
  }
}

// Pass B: per-bucket CSR, per-node pad to multiple of 4 (sentinel = N_NODES),
// per-node adjacency sorted ascending by src (L2 band locality in edge passes).
__global__ __launch_bounds__(128) void k_csr(const uint* __restrict__ pbuf,
                                             const int* __restrict__ bcursor,
                                             const int* __restrict__ bbase,
                                             int* __restrict__ rs,
                                             int* __restrict__ re,
                                             int* __restrict__ csr) {
  __shared__ int hist[NPB];
  __shared__ int excl[NPB];
  __shared__ int cur[NPB];
  __shared__ int lcsr[CAPP];
  const int b = blockIdx.x;
  const int tid = threadIdx.x;
  int count = bcursor[b] - b * CAP;
  if (count > CAP) count = CAP;
  const int gbase = bbase[b];
  const uint* seg = pbuf + b * CAP;
  hist[tid] = 0;
  __syncthreads();
  for (int k = tid; k < count; k += 128) atomicAdd(&hist[seg[k] & 127u], 1);
  __syncthreads();
  int rounded = (hist[tid] + 3) & ~3;          // pad each node to multiple of 4
  excl[tid] = rounded;
  __syncthreads();
  for (int off = 1; off < 128; off <<= 1) {
    int u = (tid >= off) ? excl[tid - off] : 0;
    __syncthreads();
    excl[tid] += u;
    __syncthreads();
  }
  int ex = excl[tid] - rounded;
  cur[tid] = ex;
  int node = b * NPB + tid;
  if (node < N_NODES) {
    rs[node] = gbase + ex;
    re[node] = gbase + ex + rounded;
  }
  __syncthreads();
  const int ptotal = excl[NPB - 1];
  for (int k = tid; k < ptotal; k += 128) lcsr[k] = N_NODES;   // sentinel fill
  __syncthreads();
  for (int k = tid; k < count; k += 128) {
    uint pk = seg[k];
    int nd = pk & 127u;
    int pos = atomicAdd(&cur[nd], 1);
    lcsr[pos] = (int)(pk >> 7);
  }
  __syncthreads();
  // per-node insertion sort of the real segment (ascending src)
  {
    int n = hist[tid];
    for (int a = ex + 1; a < ex + n; ++a) {
      int v = lcsr[a];
      int c = a - 1;
      while (c >= ex && lcsr[c] > v) { lcsr[c + 1] = lcsr[c]; --c; }
      lcsr[c + 1] = v;
    }
  }
  __syncthreads();
  for (int k = tid; k < ptotal; k += 128) csr[gbase + k] = lcsr[k];
}

// ---------------- GEMM 1 (MFMA f16) + fused alr1 + sentinel init ----------------

__global__ __launch_bounds__(256) void k_gemm1m(const float* __restrict__ x,
                                                const ushort* __restrict__ WT1,
                                                const float* __restrict__ attl,
                                                const float* __restrict__ attr,
                                                ushort* __restrict__ h1h,
                                                ushort* __restrict__ al1h,
                                                float* __restrict__ ar1) {
  __shared__ ushort stg[4][16][136];   // pad 128->136 (17 uint4/row)
  __shared__ h2_t attl_sm[64], attr_sm[64];
  const int tid = threadIdx.x;
  const int w = tid >> 6, l = tid & 63;
  const int r16 = l & 15, kq = l >> 4;
  const int rowbase = blockIdx.x * 64 + w * 16;
  if (tid < 64) attl_sm[tid] = pk2h(attl[2 * tid], attl[2 * tid + 1]);
  else if (tid < 128) { int t = tid - 64; attr_sm[t] = pk2h(attr[2 * t], attr[2 * t + 1]); }
  if (blockIdx.x == 0) {   // sentinel row N_NODES: h=0, al=-inf
    if (tid >= 128 && tid < 144) ((uint4*)h1h)[(size_t)N_NODES * 16 + (tid - 128)] = make_uint4(0, 0, 0, 0);
    else if (tid >= 144 && tid < 152) al1h[(size_t)N_NODES * 8 + (tid - 144)] = (ushort)0xFC00;  // fp16 -inf
  }
  int arow = rowbase + r16;
  if (arow > N_NODES - 1) arow = N_NODES - 1;
  f16x8 af[4];
  const float* xr = x + (size_t)arow * 128 + kq * 8;
#pragma unroll
  for (int t = 0; t < 4; ++t) {
    float4 a0 = *(const float4*)(xr + t * 32);
    float4 a1 = *(const float4*)(xr + t * 32 + 4);
    U8 u;
    u.h2[0] = pk2h(a0.x, a0.y); u.h2[1] = pk2h(a0.z, a0.w);
    u.h2[2] = pk2h(a1.x, a1.y); u.h2[3] = pk2h(a1.z, a1.w);
    af[t] = u.v;
  }
  f32x4 acc[8];
#pragma unroll
  for (int n = 0; n < 8; ++n) acc[n] = (f32x4){0.f, 0.f, 0.f, 0.f};
  const uint4* WT4 = (const uint4*)WT1;   // row = 16 uint4 (128 fp16)
#pragma unroll
  for (int t = 0; t < 4; ++t) {
#pragma unroll
    for (int n = 0; n < 8; ++n) {
      U8 b;
      b.q = WT4[(size_t)(n * 16 + r16) * 16 + t * 4 + kq];
      acc[n] = __builtin_amdgcn_mfma_f32_16x16x32_f16(af[t], b.v, acc[n], 0, 0, 0);
    }
  }
#pragma unroll
  for (int n = 0; n < 8; ++n) {
#pragma unroll
    for (int r = 0; r < 4; ++r) stg[w][kq * 4 + r][n * 16 + r16] = f2h(acc[n][r]);
  }
  __syncthreads();
  uint4* H1 = (uint4*)h1h;
  const uint4* S = (const uint4*)stg[w];   // row stride 17 uint4
#pragma unroll
  for (int q = 0; q < 4; ++q) {
    int idx = l + q * 64;
    int row = idx >> 4, c4 = idx & 15;
    int grow = rowbase + row;
    if (grow < N_NODES) H1[(size_t)grow * 16 + c4] = S[row * 17 + c4];
  }
#pragma unroll
  for (int p = 0; p < 2; ++p) {
    int pidx = l + p * 64;
    int row = pidx >> 3, h = pidx & 7;
    int grow = rowbase + row;
    U8 a0, a1;
    a0.q = S[row * 17 + h * 2];
    a1.q = S[row * 17 + h * 2 + 1];
    float sl = 0.f, sr = 0.f;
#pragma unroll
    for (int k = 0; k < 4; ++k) {
      sl = fdot2(a0.h2[k], attl_sm[h * 8 + k], sl);
      sr = fdot2(a0.h2[k], attr_sm[h * 8 + k], sr);
      sl = fdot2(a1.h2[k], attl_sm[h * 8 + 4 + k], sl);
      sr = fdot2(a1.h2[k], attr_sm[h * 8 + 4 + k], sr);
    }
    if (grow < N_NODES) {
      al1h[(size_t)grow * 8 + h] = f2h(sl);
      ar1[(size_t)grow * 8 + h] = sr;
    }
  }
}

// ---------------- edge pass, layer 1: node per 16-lane group, 4-edge steps + prefetch ----------------

__global__ __launch_bounds__(256) void k_edge1(const ushort* __restrict__ h1h,
                                               const ushort* __restrict__ alT,
                                               const float* __restrict__ ar1,
                                               const int* __restrict__ rs,
                                               const int* __restrict__ re,
                                               const int* __restrict__ csr,
                                               const float* __restrict__ b1,
                                               ushort* __restrict__ y1h) {
  const int tid = threadIdx.x;
  const int lane = tid & 63;
  const int wv = tid >> 6;
  const int grp = lane >> 4;
  const int l = lane & 15;
  const int h = l >> 1;
  const int node0 = (blockIdx.x * 4 + wv) * 4 + grp;
  const bool alive = node0 < N_NODES;
  const int i = alive ? node0 : N_NODES - 1;
  const int start = rs[i], end = re[i];
  const char* Hb = (const char*)h1h;
  const char* Ab = (const char*)alT;
  const char* Cb = (const char*)csr;
  const uint loff = (uint)l * 16u;
  const uint aoff = (uint)h * 2u;
  U8 uhi;
  uhi.q = *(const uint4*)(Hb + (uint)i * 256u + loff);
  const float ar_i = ar1[i * 8 + h];
  float s = 0.f;
  f16x8 acc = {};
  int4 ja = *(const int4*)(Cb + (uint)start * 4u);
  for (int e = start; e < end; e += 4) {
    int ep = (e + 4 < end) ? e + 4 : e;
    int4 jn = *(const int4*)(Cb + (uint)ep * 4u);
    U8 u0, u1, u2, u3;
    u0.q = *(const uint4*)(Hb + (uint)ja.x * 256u + loff);
    u1.q = *(const uint4*)(Hb + (uint)ja.y * 256u + loff);
    u2.q = *(const uint4*)(Hb + (uint)ja.z * 256u + loff);
    u3.q = *(const uint4*)(Hb + (uint)ja.w * 256u + loff);
    float av0 = h2f(*(const ushort*)(Ab + (uint)ja.x * 16u + aoff));
    float av1 = h2f(*(const ushort*)(Ab + (uint)ja.y * 16u + aoff));
    float av2 = h2f(*(const ushort*)(Ab + (uint)ja.z * 16u + aoff));
    float av3 = h2f(*(const ushort*)(Ab + (uint)ja.w * 16u + aoff));
    float p0 = 0.f, p1 = 0.f, p2 = 0.f, p3 = 0.f;
#pragma unroll
    for (int k = 0; k < 4; ++k) {
      p0 = fdot2(uhi.h2[k], u0.h2[k], p0);
      p1 = fdot2(uhi.h2[k], u1.h2[k], p1);
      p2 = fdot2(uhi.h2[k], u2.h2[k], p2);
      p3 = fdot2(uhi.h2[k], u3.h2[k], p3);
    }
    p0 += __shfl_xor(p0, 1);
    p1 += __shfl_xor(p1, 1);
    p2 += __shfl_xor(p2, 1);
    p3 += __shfl_xor(p3, 1);
    float a0 = (av0 + ar_i) * (1.f / (1.f + __expf(-p0)));
    float a1 = (av1 + ar_i) * (1.f / (1.f + __expf(-p1)));
    float a2 = (av2 + ar_i) * (1.f / (1.f + __expf(-p2)));
    float a3 = (av3 + ar_i) * (1.f / (1.f + __expf(-p3)));
    a0 = fmaxf(a0, NEG_SLOPE * a0);
    a1 = fmaxf(a1, NEG_SLOPE * a1);
    a2 = fmaxf(a2, NEG_SLOPE * a2);
    a3 = fmaxf(a3, NEG_SLOPE * a3);
    float ex0 = __expf(a0);   // sentinel: al=-inf -> ex=0
    float ex1 = __expf(a1);
    float ex2 = __expf(a2);
    float ex3 = __expf(a3);
    s += (ex0 + ex1) + (ex2 + ex3);
    acc += u0.v * (_Float16)ex0;
    acc += u1.v * (_Float16)ex1;
    acc += u2.v * (_Float16)ex2;
    acc += u3.v * (_Float16)ex3;
    ja = jn;
  }
  float inv = 1.f / s;
  float4 bb0 = *(const float4*)(b1 + l * 8);
  float4 bb1 = *(const float4*)(b1 + l * 8 + 4);
  float o[8];
#pragma unroll
  for (int c = 0; c < 8; ++c) {
    float b = (c < 4) ? ((const float*)&bb0)[c] : ((const float*)&bb1)[c - 4];
    float v = (float)acc[c] * inv + b;
    o[c] = v > 0.f ? v : __expf(v) - 1.f;       // ELU
  }
  if (alive) {
    U8 pk;
#pragma unroll
    for (int c = 0; c < 4; ++c) pk.h2[c] = pk2h(o[2 * c], o[2 * c + 1]);
    ((uint4*)y1h)[(size_t)i * 16 + l] = pk.q;
  }
}

// ---------------- GEMM 2 (MFMA f16) + fused alr2, compact 40ch (5 uint4) rows ----------------

__global__ __launch_bounds__(256) void k_gemm2m(const ushort* __restrict__ y1h,
                                                const ushort* __restrict__ WT2,
                                                const float* __restrict__ attl,
                                                const float* __restrict__ attr,
                                                ushort* __restrict__ h2p,
                                                float* __restrict__ al2,
                                                float* __restrict__ ar2) {
  __shared__ ushort stg[4][16][56];    // pad 48->56 (7 uint4/row)
  __shared__ h2_t attl_sm[20], attr_sm[20];
  const int tid = threadIdx.x;
  const int w = tid >> 6, l = tid & 63;
  const int r16 = l & 15, kq = l >> 4;
  const int rowbase = blockIdx.x * 64 + w * 16;
  if (tid < 20) attl_sm[tid] = pk2h(attl[2 * tid], attl[2 * tid + 1]);
  else if (tid >= 32 && tid < 52) { int t = tid - 32; attr_sm[t] = pk2h(attr[2 * t], attr[2 * t + 1]); }
  if (blockIdx.x == 0) {   // sentinel row: h2=0, al2=-inf
    if (tid >= 64 && tid < 69) ((uint4*)h2p)[(size_t)N_NODES * 5 + (tid - 64)] = make_uint4(0, 0, 0, 0);
    else if (tid == 69) al2[N_NODES] = -INFINITY;
  }
  int arow = rowbase + r16;
  if (arow > N_NODES - 1) arow = N_NODES - 1;
  const uint4* Y4 = (const uint4*)y1h;   // row = 16 uint4
  f16x8 af[4];
#pragma unroll
  for (int t = 0; t < 4; ++t) {
    U8 u;
    u.q = Y4[(size_t)arow * 16 + t * 4 + kq];
    af[t] = u.v;
  }
  f32x4 acc[3];
#pragma unroll
  for (int n = 0; n < 3; ++n) acc[n] = (f32x4){0.f, 0.f, 0.f, 0.f};
  const uint4* WT4 = (const uint4*)WT2;   // 48 rows x 16 uint4
#pragma unroll
  for (int t = 0; t < 4; ++t) {
#pragma unroll
    for (int n = 0; n < 3; ++n) {
      U8 b;
      b.q = WT4[(size_t)(n * 16 + r16) * 16 + t * 4 + kq];
      acc[n] = __builtin_amdgcn_mfma_f32_16x16x32_f16(af[t], b.v, acc[n], 0, 0, 0);
    }
  }
#pragma unroll
  for (int n = 0; n < 3; ++n) {
#pragma unroll
    for (int r = 0; r < 4; ++r) stg[w][kq * 4 + r][n * 16 + r16] = f2h(acc[n][r]);
  }
  __syncthreads();
  uint4* H2 = (uint4*)h2p;               // row = 5 uint4 (40 fp16, compact)
  const uint4* S = (const uint4*)stg[w]; // row stride 7 uint4
#pragma unroll
  for (int q = 0; q < 2; ++q) {
    int idx = l + q * 64;                // 0..127; active < 80
    if (idx < 80) {
      int row = idx / 5, c4 = idx % 5;
      int grow = rowbase + row;
      if (grow < N_NODES) H2[(size_t)grow * 5 + c4] = S[row * 7 + c4];
    }
  }
  // fused alr2: 16 rows x {al, ar} = 32 tasks on lanes 0..31
  if (l < 32) {
    int row = l & 15, sel = l >> 4;
    int grow = rowbase + row;
    const h2_t* att = sel ? attr_sm : attl_sm;
    float v = 0.f;
#pragma unroll
    for (int q = 0; q < 5; ++q) {
      U8 b;
      b.q = S[row * 7 + q];
#pragma unroll
      for (int k = 0; k < 4; ++k) v = fdot2(b.h2[k], att[q * 4 + k], v);
    }
    if (grow < N_NODES) {
      if (sel) ar2[grow] = v;
      else     al2[grow] = v;
    }
  }
}

// ---------------- edge pass, layer 2: node per 8-lane group, 4-edge steps + log_softmax ----------------

__global__ __launch_bounds__(256) void k_edge2(const ushort* __restrict__ h2p,
                                               const float* __restrict__ alT,
                                               const float* __restrict__ ar2,
                                               const int* __restrict__ rs,
                                               const int* __restrict__ re,
                                               const int* __restrict__ csr,
                                               const float* __restrict__ b2,
                                               float* __restrict__ out) {
  const int tid = threadIdx.x;
  const int lane = tid & 63;
  const int wv = tid >> 6;
  const int grp = lane >> 3;
  const int l = lane & 7;
  const int node0 = (blockIdx.x * 4 + wv) * 8 + grp;
  const bool alive = node0 < N_NODES;
  const int i = alive ? node0 : N_NODES - 1;
  const int start = rs[i], end = re[i];
  const char* Hb = (const char*)h2p;
  const char* Cb = (const char*)csr;
  const uint loff = (uint)(l < 5 ? l : 0) * 16u;   // lanes 5-7 duplicate uint4 0 (free, masked)
  U8 uhi;
  uhi.q = *(const uint4*)(Hb + (uint)i * 80u + loff);
  if (l >= 5) uhi.q = make_uint4(0, 0, 0, 0);      // mask -> dot contributions are 0
  const float ar_i = ar2[i];
  float s = 0.f;
  f16x8 acc = {};
  int4 ja = *(const int4*)(Cb + (uint)start * 4u);
  for (int e = start; e < end; e += 4) {
    int ep = (e + 4 < end) ? e + 4 : e;
    int4 jn = *(const int4*)(Cb + (uint)ep * 4u);
    U8 u0, u1, u2, u3;
    u0.q = *(const uint4*)(Hb + (uint)ja.x * 80u + loff);
    u1.q = *(const uint4*)(Hb + (uint)ja.y * 80u + loff);
    u2.q = *(const uint4*)(Hb + (uint)ja.z * 80u + loff);
    u3.q = *(const uint4*)(Hb + (uint)ja.w * 80u + loff);
    float av0 = alT[ja.x], av1 = alT[ja.y], av2 = alT[ja.z], av3 = alT[ja.w];
    float p0 = 0.f, p1 = 0.f, p2 = 0.f, p3 = 0.f;
#pragma unroll
    for (int k = 0; k < 4; ++k) {
      p0 = fdot2(uhi.h2[k], u0.h2[k], p0);
      p1 = fdot2(uhi.h2[k], u1.h2[k], p1);
      p2 = fdot2(uhi.h2[k], u2.h2[k], p2);
      p3 = fdot2(uhi.h2[k], u3.h2[k], p3);
    }
#pragma unroll
    for (int m = 1; m <= 4; m <<= 1) {
      p0 += __shfl_xor(p0, m);
      p1 += __shfl_xor(p1, m);
      p2 += __shfl_xor(p2, m);
      p3 += __shfl_xor(p3, m);
    }
    float a0 = (av0 + ar_i) * (1.f / (1.f + __expf(-p0)));
    float a1 = (av1 + ar_i) * (1.f / (1.f + __expf(-p1)));
    float a2 = (av2 + ar_i) * (1.f / (1.f + __expf(-p2)));
    float a3 = (av3 + ar_i) * (1.f / (1.f + __expf(-p3)));
    a0 = fmaxf(a0, NEG_SLOPE * a0);
    a1 = fmaxf(a1, NEG_SLOPE * a1);
    a2 = fmaxf(a2, NEG_SLOPE * a2);
    a3 = fmaxf(a3, NEG_SLOPE * a3);
    float ex0 = __expf(a0);   // sentinel: al=-inf -> ex=0
    float ex1 = __expf(a1);
    float ex2 = __expf(a2);
    float ex3 = __expf(a3);
    s += (ex0 + ex1) + (ex2 + ex3);
    acc += u0.v * (_Float16)ex0;
    acc += u1.v * (_Float16)ex1;
    acc += u2.v * (_Float16)ex2;
    acc += u3.v * (_Float16)ex3;
    ja = jn;
  }
  // epilogue: bias + log_softmax over 40 classes (group-local)
  float inv = 1.f / s;
  bool act = l < 5;
  float o[8];
  float mx = -1e30f;
#pragma unroll
  for (int c = 0; c < 8; ++c) {
    float b = act ? b2[l * 8 + c] : 0.f;
    o[c] = (float)acc[c] * inv + b;
    if (act) mx = fmaxf(mx, o[c]);
  }
  mx = fmaxf(mx, __shfl_xor(mx, 1));
  mx = fmaxf(mx, __shfl_xor(mx, 2));
  mx = fmaxf(mx, __shfl_xor(mx, 4));
  float se = 0.f;
  if (act) {
#pragma unroll
    for (int c = 0; c < 8; ++c) se += __expf(o[c] - mx);
  }
  se += __shfl_xor(se, 1);
  se += __shfl_xor(se, 2);
  se += __shfl_xor(se, 4);
  if (alive && act) {
    float lse = mx + __logf(se);
    float4 r0 = make_float4(o[0] - lse, o[1] - lse, o[2] - lse, o[3] - lse);
    float4 r1 = make_float4(o[4] - lse, o[5] - lse, o[6] - lse, o[7] - lse);
    float4* O = (float4*)(out + (size_t)i * 40 + l * 8);
    O[0] = r0;
    O[1] = r1;
  }
}

// ---------------- launcher ----------------

extern "C" void kernel_launch(void* const* d_in, const int* in_sizes, int n_in,
                              void* d_out, int out_size, void* d_ws, size_t ws_size,
                              hipStream_t stream) {
  const float* x     = (const float*)d_in[0];
  const int*   ei    = (const int*)d_in[1];
  const float* W1    = (const float*)d_in[2];
  const float* attl1 = (const float*)d_in[3];
  const float* attr1 = (const float*)d_in[4];
  const float* b1    = (const float*)d_in[5];
  const float* W2    = (const float*)d_in[6];
  const float* attl2 = (const float*)d_in[7];
  const float* attr2 = (const float*)d_in[8];
  const float* b2    = (const float*)d_in[9];
  float* out = (float*)d_out;

  char* wsp = (char*)d_ws;
  size_t off = 0;
  auto alloc = [&](size_t bytes) {
    char* p = wsp + off;
    off = (off + bytes + 255) & ~(size_t)255;
    return p;
  };
  ushort* h1h   = (ushort*)alloc((size_t)(N_NODES + 1) * 128 * 2);  // fp16 h1 (+sentinel row)
  ushort* y1h   = (ushort*)alloc((size_t)N_NODES * 128 * 2);        // fp16 y1
  ushort* al1h  = (ushort*)alloc((size_t)(N_NODES + 1) * 8 * 2);    // fp16 al1 (+sentinel)
  float* ar1    = (float*)alloc((size_t)N_NODES * 8 * 4);
  int* rs       = (int*)alloc((size_t)(N_NODES + 4) * 4);
  int* re       = (int*)alloc((size_t)(N_NODES + 4) * 4);
  int* bcursor  = (int*)alloc((size_t)NB * 4);
  int* bbase    = (int*)alloc((size_t)NB * 4);
  int* csr      = (int*)alloc((size_t)(E2 + NB * BSLACK + 16) * 4); // padded CSR
  ushort* WT1   = (ushort*)alloc(128 * 128 * 2);
  ushort* WT2   = (ushort*)alloc(48 * 128 * 2);
  uint* pbuf  = (uint*)y1h;   // overlay: pbuf (8.1MB) dead before edge1 writes y1h
  ushort* h2p = h1h;          // reuse: h1h dead after edge1 ((N+1)*80B <= (N+1)*256B)
  float* al2  = (float*)ar1;  // reuse: ar1/al1h dead after edge1; needs N+1 floats
  float* ar2  = al2 + N_NODES + 8;

  // prep + CSR build
  k_prepW<<<3, 256, 0, stream>>>(W1, W2, WT1, WT2, bcursor);
  k_bucket<<<(E2 + BCH - 1) / BCH, 256, 0, stream>>>(ei, bcursor, pbuf);
  k_scanB<<<1, 1024, 0, stream>>>(bcursor, bbase);
  k_csr<<<NB, 128, 0, stream>>>(pbuf, bcursor, bbase, rs, re, csr);

  // layer 1
  k_gemm1m<<<(N_NODES + 63) / 64, 256, 0, stream>>>(x, WT1, attl1, attr1, h1h, al1h, ar1);
  k_edge1<<<(N_NODES + 15) / 16, 256, 0, stream>>>(h1h, al1h, ar1, rs, re, csr, b1, y1h);

  // layer 2
  k_gemm2m<<<(N_NODES + 63) / 64, 256, 0, stream>>>(y1h, WT2, attl2, attr2, h2p, al2, ar2);
  k_edge2<<<(N_NODES + 31) / 32, 256, 0, stream>>>(h2p, al2, ar2, rs, re, csr, b2, out);
}

// Round 15
// 229.494 us; speedup vs baseline: 1.1915x; 1.1915x over previous
//
#include <hip/hip_runtime.h>
#include <math.h>

#define N_NODES 100000
#define N_EDGES 1600000
#define E2 (N_EDGES + N_NODES)
#define NEG_SLOPE 0.2f

#define NPB 128                      // nodes per bucket
#define NB  ((N_NODES + NPB - 1) / NPB)   // 782 buckets
#define CAP 2600                     // per-bucket raw edge capacity (mean ~2227, +8 sigma)
#define CAPP (CAP + 3 * NPB)         // padded capacity (2984)
#define BSLACK (3 * NPB + 4)         // per-bucket slack in final CSR (388)
#define BCH 4096                     // edges per block in k_bucket (LDS-cached)

typedef unsigned int uint;
typedef unsigned short ushort;
typedef __attribute__((ext_vector_type(2))) _Float16 h2_t;
typedef __attribute__((ext_vector_type(8))) _Float16 f16x8;
typedef __attribute__((ext_vector_type(4))) float f32x4;

union U8 { uint4 q; f16x8 v; h2_t h2[4]; _Float16 h[8]; uint u[4]; };

// ---------------- fp16 helpers ----------------

__device__ inline ushort f2h(float x) {
  _Float16 h = (_Float16)x;
  return *(ushort*)&h;
}

__device__ inline float h2f(ushort u) {
  _Float16 h = *(_Float16*)&u;
  return (float)h;
}

__device__ inline h2_t pk2h(float a, float b) {
  auto r = __builtin_amdgcn_cvt_pkrtz(a, b);   // __fp16 vec2 -> bit-cast
  return *(h2_t*)&r;
}

__device__ inline float fdot2(h2_t a, h2_t b, float c) {
#if __has_builtin(__builtin_amdgcn_fdot2)
  return __builtin_amdgcn_fdot2(*(__fp16 __attribute__((ext_vector_type(2)))*)&a,
                                *(__fp16 __attribute__((ext_vector_type(2)))*)&b,
                                c, false);
#else
  return c + (float)a.x * (float)b.x + (float)a.y * (float)b.y;
#endif
}

// ---------------- prep: W transposes (fp16) + bucket cursor init ----------------

__global__ __launch_bounds__(256) void k_prepW(const float* __restrict__ W1,
                                               const float* __restrict__ W2,
                                               ushort* __restrict__ WT1,
                                               ushort* __restrict__ WT2,
                                               int* __restrict__ bcursor) {
  int b = blockIdx.x, t = threadIdx.x;
  if (b == 0) {
    for (int i = t; i < 128 * 128; i += 256) {
      int k = i >> 7, n = i & 127;
      WT1[n * 128 + k] = f2h(W1[i]);           // WT1[n][k]
    }
  } else if (b == 1) {
    for (int i = t; i < 48 * 128; i += 256) {
      int n = i >> 7, k = i & 127;
      WT2[i] = (n < 40) ? f2h(W2[k * 40 + n]) : (ushort)0;   // WT2[n][k], zero-pad n>=40
    }
  } else {
    for (int i = t; i < NB; i += 256) bcursor[i] = i * CAP;
  }
}

// ---------------- bucketed CSR construction (single global pass, LDS edge cache) ----------------

__global__ __launch_bounds__(256) void k_bucket(const int* __restrict__ ei,
                                                int* __restrict__ bcursor,
                                                uint* __restrict__ pbuf) {
  __shared__ uint pay[BCH];
  __shared__ ushort bkt[BCH];
  __shared__ int cnt[NB];
  __shared__ int base[NB];
  const int tid = threadIdx.x;
  const int ebase = blockIdx.x * BCH;
  for (int t = tid; t < NB; t += 256) cnt[t] = 0;
  __syncthreads();
#pragma unroll 4
  for (int k = 0; k < BCH / 256; ++k) {
    int idx = tid + k * 256;
    int e = ebase + idx;
    if (e < E2) {
      int s, d;
      if (e < N_EDGES) { s = ei[e]; d = ei[N_EDGES + e]; }
      else { s = e - N_EDGES; d = s; }
      pay[idx] = ((uint)s << 7) | (uint)(d & 127);
      int b = d >> 7;
      bkt[idx] = (ushort)b;
      atomicAdd(&cnt[b], 1);
    } else {
      bkt[idx] = 0xFFFFu;
    }
  }
  __syncthreads();
  for (int t = tid; t < NB; t += 256) {
    int c = cnt[t];
    base[t] = c ? atomicAdd(&bcursor[t], c) : 0;
    cnt[t] = 0;
  }
  __syncthreads();
#pragma unroll 4
  for (int k = 0; k < BCH / 256; ++k) {
    int idx = tid + k * 256;
    ushort b = bkt[idx];
    if (b != 0xFFFFu) {
      int pos = base[b] + atomicAdd(&cnt[b], 1);
      pbuf[pos] = pay[idx];
    }
  }
}

__global__ __launch_bounds__(1024) void k_scanB(const int* __restrict__ bcursor,
                                                int* __restrict__ bbase) {
  __shared__ int sm[1024];
  int t = threadIdx.x;
  int v = (t < NB) ? (bcursor[t] - t * CAP) : 0;
  sm[t] = v;
  __syncthreads();
  for (int off = 1; off < 1024; off <<= 1) {
    int u = (t >= off) ? sm[t - off] : 0;
    __syncthreads();
    sm[t] += u;
    __syncthreads();
  }
  if (t < NB) {
    int excl = sm[t] - v;
    bbase[t] = ((excl + 3) & ~3) + t * BSLACK;   // 16B-aligned start + per-bucket pad slack
  }
}

// Pass B: per-bucket CSR, per-node pad to multiple of 4 (sentinel = N_NODES). 128 threads/block.
__global__ __launch_bounds__(128) void k_csr(const uint* __restrict__ pbuf,
                                             const int* __restrict__ bcursor,
                                             const int* __restrict__ bbase,
                                             int* __restrict__ rs,
                                             int* __restrict__ re,
                                             int* __restrict__ csr) {
  __shared__ int hist[NPB];
  __shared__ int excl[NPB];
  __shared__ int cur[NPB];
  __shared__ int lcsr[CAPP];
  const int b = blockIdx.x;
  const int tid = threadIdx.x;
  int count = bcursor[b] - b * CAP;
  if (count > CAP) count = CAP;
  const int gbase = bbase[b];
  const uint* seg = pbuf + b * CAP;
  hist[tid] = 0;
  __syncthreads();
  for (int k = tid; k < count; k += 128) atomicAdd(&hist[seg[k] & 127u], 1);
  __syncthreads();
  int rounded = (hist[tid] + 3) & ~3;          // pad each node to multiple of 4
  excl[tid] = rounded;
  __syncthreads();
  for (int off = 1; off < 128; off <<= 1) {
    int u = (tid >= off) ? excl[tid - off] : 0;
    __syncthreads();
    excl[tid] += u;
    __syncthreads();
  }
  int ex = excl[tid] - rounded;
  cur[tid] = ex;
  int node = b * NPB + tid;
  if (node < N_NODES) {
    rs[node] = gbase + ex;
    re[node] = gbase + ex + rounded;
  }
  __syncthreads();
  const int ptotal = excl[NPB - 1];
  for (int k = tid; k < ptotal; k += 128) lcsr[k] = N_NODES;   // sentinel fill
  __syncthreads();
  for (int k = tid; k < count; k += 128) {
    uint pk = seg[k];
    int nd = pk & 127u;
    int pos = atomicAdd(&cur[nd], 1);
    lcsr[pos] = (int)(pk >> 7);
  }
  __syncthreads();
  for (int k = tid; k < ptotal; k += 128) csr[gbase + k] = lcsr[k];
}

// ---------------- GEMM 1 (MFMA f16) + fused alr1 + sentinel init ----------------

__global__ __launch_bounds__(256) void k_gemm1m(const float* __restrict__ x,
                                                const ushort* __restrict__ WT1,
                                                const float* __restrict__ attl,
                                                const float* __restrict__ attr,
                                                ushort* __restrict__ h1h,
                                                ushort* __restrict__ al1h,
                                                float* __restrict__ ar1) {
  __shared__ ushort stg[4][16][136];   // pad 128->136 (17 uint4/row)
  __shared__ h2_t attl_sm[64], attr_sm[64];
  const int tid = threadIdx.x;
  const int w = tid >> 6, l = tid & 63;
  const int r16 = l & 15, kq = l >> 4;
  const int rowbase = blockIdx.x * 64 + w * 16;
  if (tid < 64) attl_sm[tid] = pk2h(attl[2 * tid], attl[2 * tid + 1]);
  else if (tid < 128) { int t = tid - 64; attr_sm[t] = pk2h(attr[2 * t], attr[2 * t + 1]); }
  if (blockIdx.x == 0) {   // sentinel row N_NODES: h=0, al=-inf
    if (tid >= 128 && tid < 144) ((uint4*)h1h)[(size_t)N_NODES * 16 + (tid - 128)] = make_uint4(0, 0, 0, 0);
    else if (tid >= 144 && tid < 152) al1h[(size_t)N_NODES * 8 + (tid - 144)] = (ushort)0xFC00;  // fp16 -inf
  }
  int arow = rowbase + r16;
  if (arow > N_NODES - 1) arow = N_NODES - 1;
  f16x8 af[4];
  const float* xr = x + (size_t)arow * 128 + kq * 8;
#pragma unroll
  for (int t = 0; t < 4; ++t) {
    float4 a0 = *(const float4*)(xr + t * 32);
    float4 a1 = *(const float4*)(xr + t * 32 + 4);
    U8 u;
    u.h2[0] = pk2h(a0.x, a0.y); u.h2[1] = pk2h(a0.z, a0.w);
    u.h2[2] = pk2h(a1.x, a1.y); u.h2[3] = pk2h(a1.z, a1.w);
    af[t] = u.v;
  }
  f32x4 acc[8];
#pragma unroll
  for (int n = 0; n < 8; ++n) acc[n] = (f32x4){0.f, 0.f, 0.f, 0.f};
  const uint4* WT4 = (const uint4*)WT1;   // row = 16 uint4 (128 fp16)
#pragma unroll
  for (int t = 0; t < 4; ++t) {
#pragma unroll
    for (int n = 0; n < 8; ++n) {
      U8 b;
      b.q = WT4[(size_t)(n * 16 + r16) * 16 + t * 4 + kq];
      acc[n] = __builtin_amdgcn_mfma_f32_16x16x32_f16(af[t], b.v, acc[n], 0, 0, 0);
    }
  }
#pragma unroll
  for (int n = 0; n < 8; ++n) {
#pragma unroll
    for (int r = 0; r < 4; ++r) stg[w][kq * 4 + r][n * 16 + r16] = f2h(acc[n][r]);
  }
  __syncthreads();
  uint4* H1 = (uint4*)h1h;
  const uint4* S = (const uint4*)stg[w];   // row stride 17 uint4
#pragma unroll
  for (int q = 0; q < 4; ++q) {
    int idx = l + q * 64;
    int row = idx >> 4, c4 = idx & 15;
    int grow = rowbase + row;
    if (grow < N_NODES) H1[(size_t)grow * 16 + c4] = S[row * 17 + c4];
  }
#pragma unroll
  for (int p = 0; p < 2; ++p) {
    int pidx = l + p * 64;
    int row = pidx >> 3, h = pidx & 7;
    int grow = rowbase + row;
    U8 a0, a1;
    a0.q = S[row * 17 + h * 2];
    a1.q = S[row * 17 + h * 2 + 1];
    float sl = 0.f, sr = 0.f;
#pragma unroll
    for (int k = 0; k < 4; ++k) {
      sl = fdot2(a0.h2[k], attl_sm[h * 8 + k], sl);
      sr = fdot2(a0.h2[k], attr_sm[h * 8 + k], sr);
      sl = fdot2(a1.h2[k], attl_sm[h * 8 + 4 + k], sl);
      sr = fdot2(a1.h2[k], attr_sm[h * 8 + 4 + k], sr);
    }
    if (grow < N_NODES) {
      al1h[(size_t)grow * 8 + h] = f2h(sl);
      ar1[(size_t)grow * 8 + h] = sr;
    }
  }
}

// ---------------- edge pass, layer 1: node per 16-lane group, loop-carried row prefetch ----------------

__global__ __launch_bounds__(256, 4) void k_edge1(const ushort* __restrict__ h1h,
                                                  const ushort* __restrict__ alT,
                                                  const float* __restrict__ ar1,
                                                  const int* __restrict__ rs,
                                                  const int* __restrict__ re,
                                                  const int* __restrict__ csr,
                                                  const float* __restrict__ b1,
                                                  ushort* __restrict__ y1h) {
  const int tid = threadIdx.x;
  const int lane = tid & 63;
  const int wv = tid >> 6;
  const int grp = lane >> 4;
  const int l = lane & 15;
  const int h = l >> 1;
  const int node0 = (blockIdx.x * 4 + wv) * 4 + grp;
  const bool alive = node0 < N_NODES;
  const int i = alive ? node0 : N_NODES - 1;
  const int start = rs[i], end = re[i];
  const char* Hb = (const char*)h1h;
  const char* Ab = (const char*)alT;
  const char* Cb = (const char*)csr;
  const uint loff = (uint)l * 16u;
  const uint aoff = (uint)h * 2u;
  U8 uhi;
  uhi.q = *(const uint4*)(Hb + (uint)i * 256u + loff);
  const float ar_i = ar1[i * 8 + h];
  float s = 0.f;
  f16x8 acc = {};
  // prologue: load iteration 0's rows + al into the carried buffer
  int4 ja = *(const int4*)(Cb + (uint)start * 4u);
  U8 c0, c1, c2, c3;
  c0.q = *(const uint4*)(Hb + (uint)ja.x * 256u + loff);
  c1.q = *(const uint4*)(Hb + (uint)ja.y * 256u + loff);
  c2.q = *(const uint4*)(Hb + (uint)ja.z * 256u + loff);
  c3.q = *(const uint4*)(Hb + (uint)ja.w * 256u + loff);
  float w0 = h2f(*(const ushort*)(Ab + (uint)ja.x * 16u + aoff));
  float w1 = h2f(*(const ushort*)(Ab + (uint)ja.y * 16u + aoff));
  float w2 = h2f(*(const ushort*)(Ab + (uint)ja.z * 16u + aoff));
  float w3 = h2f(*(const ushort*)(Ab + (uint)ja.w * 16u + aoff));
  for (int e = start; e < end; e += 4) {
    // issue next iteration's gathers (loop-carried)
    int ep = (e + 4 < end) ? e + 4 : e;
    int4 jn = *(const int4*)(Cb + (uint)ep * 4u);
    U8 n0, n1, n2, n3;
    n0.q = *(const uint4*)(Hb + (uint)jn.x * 256u + loff);
    n1.q = *(const uint4*)(Hb + (uint)jn.y * 256u + loff);
    n2.q = *(const uint4*)(Hb + (uint)jn.z * 256u + loff);
    n3.q = *(const uint4*)(Hb + (uint)jn.w * 256u + loff);
    float nw0 = h2f(*(const ushort*)(Ab + (uint)jn.x * 16u + aoff));
    float nw1 = h2f(*(const ushort*)(Ab + (uint)jn.y * 16u + aoff));
    float nw2 = h2f(*(const ushort*)(Ab + (uint)jn.z * 16u + aoff));
    float nw3 = h2f(*(const ushort*)(Ab + (uint)jn.w * 16u + aoff));
    // compute on current buffer
    float p0 = 0.f, p1 = 0.f, p2 = 0.f, p3 = 0.f;
#pragma unroll
    for (int k = 0; k < 4; ++k) {
      p0 = fdot2(uhi.h2[k], c0.h2[k], p0);
      p1 = fdot2(uhi.h2[k], c1.h2[k], p1);
      p2 = fdot2(uhi.h2[k], c2.h2[k], p2);
      p3 = fdot2(uhi.h2[k], c3.h2[k], p3);
    }
    p0 += __shfl_xor(p0, 1);
    p1 += __shfl_xor(p1, 1);
    p2 += __shfl_xor(p2, 1);
    p3 += __shfl_xor(p3, 1);
    float a0 = (w0 + ar_i) * (1.f / (1.f + __expf(-p0)));
    float a1 = (w1 + ar_i) * (1.f / (1.f + __expf(-p1)));
    float a2 = (w2 + ar_i) * (1.f / (1.f + __expf(-p2)));
    float a3 = (w3 + ar_i) * (1.f / (1.f + __expf(-p3)));
    a0 = fmaxf(a0, NEG_SLOPE * a0);
    a1 = fmaxf(a1, NEG_SLOPE * a1);
    a2 = fmaxf(a2, NEG_SLOPE * a2);
    a3 = fmaxf(a3, NEG_SLOPE * a3);
    float ex0 = __expf(a0);   // sentinel: al=-inf -> ex=0
    float ex1 = __expf(a1);
    float ex2 = __expf(a2);
    float ex3 = __expf(a3);
    s += (ex0 + ex1) + (ex2 + ex3);
    acc += c0.v * (_Float16)ex0;
    acc += c1.v * (_Float16)ex1;
    acc += c2.v * (_Float16)ex2;
    acc += c3.v * (_Float16)ex3;
    // rotate buffers
    c0 = n0; c1 = n1; c2 = n2; c3 = n3;
    w0 = nw0; w1 = nw1; w2 = nw2; w3 = nw3;
  }
  float inv = 1.f / s;
  float4 bb0 = *(const float4*)(b1 + l * 8);
  float4 bb1 = *(const float4*)(b1 + l * 8 + 4);
  float o[8];
#pragma unroll
  for (int c = 0; c < 8; ++c) {
    float b = (c < 4) ? ((const float*)&bb0)[c] : ((const float*)&bb1)[c - 4];
    float v = (float)acc[c] * inv + b;
    o[c] = v > 0.f ? v : __expf(v) - 1.f;       // ELU
  }
  if (alive) {
    U8 pk;
#pragma unroll
    for (int c = 0; c < 4; ++c) pk.h2[c] = pk2h(o[2 * c], o[2 * c + 1]);
    ((uint4*)y1h)[(size_t)i * 16 + l] = pk.q;
  }
}

// ---------------- GEMM 2 (MFMA f16) + fused alr2, compact 40ch (5 uint4) rows ----------------

__global__ __launch_bounds__(256) void k_gemm2m(const ushort* __restrict__ y1h,
                                                const ushort* __restrict__ WT2,
                                                const float* __restrict__ attl,
                                                const float* __restrict__ attr,
                                                ushort* __restrict__ h2p,
                                                float* __restrict__ al2,
                                                float* __restrict__ ar2) {
  __shared__ ushort stg[4][16][56];    // pad 48->56 (7 uint4/row)
  __shared__ h2_t attl_sm[20], attr_sm[20];
  const int tid = threadIdx.x;
  const int w = tid >> 6, l = tid & 63;
  const int r16 = l & 15, kq = l >> 4;
  const int rowbase = blockIdx.x * 64 + w * 16;
  if (tid < 20) attl_sm[tid] = pk2h(attl[2 * tid], attl[2 * tid + 1]);
  else if (tid >= 32 && tid < 52) { int t = tid - 32; attr_sm[t] = pk2h(attr[2 * t], attr[2 * t + 1]); }
  if (blockIdx.x == 0) {   // sentinel row: h2=0, al2=-inf
    if (tid >= 64 && tid < 69) ((uint4*)h2p)[(size_t)N_NODES * 5 + (tid - 64)] = make_uint4(0, 0, 0, 0);
    else if (tid == 69) al2[N_NODES] = -INFINITY;
  }
  int arow = rowbase + r16;
  if (arow > N_NODES - 1) arow = N_NODES - 1;
  const uint4* Y4 = (const uint4*)y1h;   // row = 16 uint4
  f16x8 af[4];
#pragma unroll
  for (int t = 0; t < 4; ++t) {
    U8 u;
    u.q = Y4[(size_t)arow * 16 + t * 4 + kq];
    af[t] = u.v;
  }
  f32x4 acc[3];
#pragma unroll
  for (int n = 0; n < 3; ++n) acc[n] = (f32x4){0.f, 0.f, 0.f, 0.f};
  const uint4* WT4 = (const uint4*)WT2;   // 48 rows x 16 uint4
#pragma unroll
  for (int t = 0; t < 4; ++t) {
#pragma unroll
    for (int n = 0; n < 3; ++n) {
      U8 b;
      b.q = WT4[(size_t)(n * 16 + r16) * 16 + t * 4 + kq];
      acc[n] = __builtin_amdgcn_mfma_f32_16x16x32_f16(af[t], b.v, acc[n], 0, 0, 0);
    }
  }
#pragma unroll
  for (int n = 0; n < 3; ++n) {
#pragma unroll
    for (int r = 0; r < 4; ++r) stg[w][kq * 4 + r][n * 16 + r16] = f2h(acc[n][r]);
  }
  __syncthreads();
  uint4* H2 = (uint4*)h2p;               // row = 5 uint4 (40 fp16, compact)
  const uint4* S = (const uint4*)stg[w]; // row stride 7 uint4
#pragma unroll
  for (int q = 0; q < 2; ++q) {
    int idx = l + q * 64;                // 0..127; active < 80
    if (idx < 80) {
      int row = idx / 5, c4 = idx % 5;
      int grow = rowbase + row;
      if (grow < N_NODES) H2[(size_t)grow * 5 + c4] = S[row * 7 + c4];
    }
  }
  // fused alr2: 16 rows x {al, ar} = 32 tasks on lanes 0..31
  if (l < 32) {
    int row = l & 15, sel = l >> 4;
    int grow = rowbase + row;
    const h2_t* att = sel ? attr_sm : attl_sm;
    float v = 0.f;
#pragma unroll
    for (int q = 0; q < 5; ++q) {
      U8 b;
      b.q = S[row * 7 + q];
#pragma unroll
      for (int k = 0; k < 4; ++k) v = fdot2(b.h2[k], att[q * 4 + k], v);
    }
    if (grow < N_NODES) {
      if (sel) ar2[grow] = v;
      else     al2[grow] = v;
    }
  }
}

// ---------------- edge pass, layer 2: node per 8-lane group, loop-carried prefetch + log_softmax ----------------

__global__ __launch_bounds__(256, 4) void k_edge2(const ushort* __restrict__ h2p,
                                                  const float* __restrict__ alT,
                                                  const float* __restrict__ ar2,
                                                  const int* __restrict__ rs,
                                                  const int* __restrict__ re,
                                                  const int* __restrict__ csr,
                                                  const float* __restrict__ b2,
                                                  float* __restrict__ out) {
  const int tid = threadIdx.x;
  const int lane = tid & 63;
  const int wv = tid >> 6;
  const int grp = lane >> 3;
  const int l = lane & 7;
  const int node0 = (blockIdx.x * 4 + wv) * 8 + grp;
  const bool alive = node0 < N_NODES;
  const int i = alive ? node0 : N_NODES - 1;
  const int start = rs[i], end = re[i];
  const char* Hb = (const char*)h2p;
  const char* Cb = (const char*)csr;
  const uint loff = (uint)(l < 5 ? l : 0) * 16u;   // lanes 5-7 duplicate uint4 0 (free, masked)
  U8 uhi;
  uhi.q = *(const uint4*)(Hb + (uint)i * 80u + loff);
  if (l >= 5) uhi.q = make_uint4(0, 0, 0, 0);      // mask -> dot contributions are 0
  const float ar_i = ar2[i];
  float s = 0.f;
  f16x8 acc = {};
  int4 ja = *(const int4*)(Cb + (uint)start * 4u);
  U8 c0, c1, c2, c3;
  c0.q = *(const uint4*)(Hb + (uint)ja.x * 80u + loff);
  c1.q = *(const uint4*)(Hb + (uint)ja.y * 80u + loff);
  c2.q = *(const uint4*)(Hb + (uint)ja.z * 80u + loff);
  c3.q = *(const uint4*)(Hb + (uint)ja.w * 80u + loff);
  float w0 = alT[ja.x], w1 = alT[ja.y], w2 = alT[ja.z], w3 = alT[ja.w];
  for (int e = start; e < end; e += 4) {
    int ep = (e + 4 < end) ? e + 4 : e;
    int4 jn = *(const int4*)(Cb + (uint)ep * 4u);
    U8 n0, n1, n2, n3;
    n0.q = *(const uint4*)(Hb + (uint)jn.x * 80u + loff);
    n1.q = *(const uint4*)(Hb + (uint)jn.y * 80u + loff);
    n2.q = *(const uint4*)(Hb + (uint)jn.z * 80u + loff);
    n3.q = *(const uint4*)(Hb + (uint)jn.w * 80u + loff);
    float nw0 = alT[jn.x], nw1 = alT[jn.y], nw2 = alT[jn.z], nw3 = alT[jn.w];
    float p0 = 0.f, p1 = 0.f, p2 = 0.f, p3 = 0.f;
#pragma unroll
    for (int k = 0; k < 4; ++k) {
      p0 = fdot2(uhi.h2[k], c0.h2[k], p0);
      p1 = fdot2(uhi.h2[k], c1.h2[k], p1);
      p2 = fdot2(uhi.h2[k], c2.h2[k], p2);
      p3 = fdot2(uhi.h2[k], c3.h2[k], p3);
    }
#pragma unroll
    for (int m = 1; m <= 4; m <<= 1) {
      p0 += __shfl_xor(p0, m);
      p1 += __shfl_xor(p1, m);
      p2 += __shfl_xor(p2, m);
      p3 += __shfl_xor(p3, m);
    }
    float a0 = (w0 + ar_i) * (1.f / (1.f + __expf(-p0)));
    float a1 = (w1 + ar_i) * (1.f / (1.f + __expf(-p1)));
    float a2 = (w2 + ar_i) * (1.f / (1.f + __expf(-p2)));
    float a3 = (w3 + ar_i) * (1.f / (1.f + __expf(-p3)));
    a0 = fmaxf(a0, NEG_SLOPE * a0);
    a1 = fmaxf(a1, NEG_SLOPE * a1);
    a2 = fmaxf(a2, NEG_SLOPE * a2);
    a3 = fmaxf(a3, NEG_SLOPE * a3);
    float ex0 = __expf(a0);   // sentinel: al=-inf -> ex=0
    float ex1 = __expf(a1);
    float ex2 = __expf(a2);
    float ex3 = __expf(a3);
    s += (ex0 + ex1) + (ex2 + ex3);
    acc += c0.v * (_Float16)ex0;
    acc += c1.v * (_Float16)ex1;
    acc += c2.v * (_Float16)ex2;
    acc += c3.v * (_Float16)ex3;
    c0 = n0; c1 = n1; c2 = n2; c3 = n3;
    w0 = nw0; w1 = nw1; w2 = nw2; w3 = nw3;
  }
  // epilogue: bias + log_softmax over 40 classes (group-local)
  float inv = 1.f / s;
  bool act = l < 5;
  float o[8];
  float mx = -1e30f;
#pragma unroll
  for (int c = 0; c < 8; ++c) {
    float b = act ? b2[l * 8 + c] : 0.f;
    o[c] = (float)acc[c] * inv + b;
    if (act) mx = fmaxf(mx, o[c]);
  }
  mx = fmaxf(mx, __shfl_xor(mx, 1));
  mx = fmaxf(mx, __shfl_xor(mx, 2));
  mx = fmaxf(mx, __shfl_xor(mx, 4));
  float se = 0.f;
  if (act) {
#pragma unroll
    for (int c = 0; c < 8; ++c) se += __expf(o[c] - mx);
  }
  se += __shfl_xor(se, 1);
  se += __shfl_xor(se, 2);
  se += __shfl_xor(se, 4);
  if (alive && act) {
    float lse = mx + __logf(se);
    float4 r0 = make_float4(o[0] - lse, o[1] - lse, o[2] - lse, o[3] - lse);
    float4 r1 = make_float4(o[4] - lse, o[5] - lse, o[6] - lse, o[7] - lse);
    float4* O = (float4*)(out + (size_t)i * 40 + l * 8);
    O[0] = r0;
    O[1] = r1;
  }
}

// ---------------- launcher ----------------

extern "C" void kernel_launch(void* const* d_in, const int* in_sizes, int n_in,
                              void* d_out, int out_size, void* d_ws, size_t ws_size,
                              hipStream_t stream) {
  const float* x     = (const float*)d_in[0];
  const int*   ei    = (const int*)d_in[1];
  const float* W1    = (const float*)d_in[2];
  const float* attl1 = (const float*)d_in[3];
  const float* attr1 = (const float*)d_in[4];
  const float* b1    = (const float*)d_in[5];
  const float* W2    = (const float*)d_in[6];
  const float* attl2 = (const float*)d_in[7];
  const float* attr2 = (const float*)d_in[8];
  const float* b2    = (const float*)d_in[9];
  float* out = (float*)d_out;

  char* wsp = (char*)d_ws;
  size_t off = 0;
  auto alloc = [&](size_t bytes) {
    char* p = wsp + off;
    off = (off + bytes + 255) & ~(size_t)255;
    return p;
  };
  ushort* h1h   = (ushort*)alloc((size_t)(N_NODES + 1) * 128 * 2);  // fp16 h1 (+sentinel row)
  ushort* y1h   = (ushort*)alloc((size_t)N_NODES * 128 * 2);        // fp16 y1
  ushort* al1h  = (ushort*)alloc((size_t)(N_NODES + 1) * 8 * 2);    // fp16 al1 (+sentinel)
  float* ar1    = (float*)alloc((size_t)N_NODES * 8 * 4);
  int* rs       = (int*)alloc((size_t)(N_NODES + 4) * 4);
  int* re       = (int*)alloc((size_t)(N_NODES + 4) * 4);
  int* bcursor  = (int*)alloc((size_t)NB * 4);
  int* bbase    = (int*)alloc((size_t)NB * 4);
  int* csr      = (int*)alloc((size_t)(E2 + NB * BSLACK + 16) * 4); // padded CSR
  ushort* WT1   = (ushort*)alloc(128 * 128 * 2);
  ushort* WT2   = (ushort*)alloc(48 * 128 * 2);
  uint* pbuf  = (uint*)y1h;   // overlay: pbuf (8.1MB) dead before edge1 writes y1h
  ushort* h2p = h1h;          // reuse: h1h dead after edge1 ((N+1)*80B <= (N+1)*256B)
  float* al2  = (float*)ar1;  // reuse: ar1/al1h dead after edge1; needs N+1 floats
  float* ar2  = al2 + N_NODES + 8;

  // prep + CSR build
  k_prepW<<<3, 256, 0, stream>>>(W1, W2, WT1, WT2, bcursor);
  k_bucket<<<(E2 + BCH - 1) / BCH, 256, 0, stream>>>(ei, bcursor, pbuf);
  k_scanB<<<1, 1024, 0, stream>>>(bcursor, bbase);
  k_csr<<<NB, 128, 0, stream>>>(pbuf, bcursor, bbase, rs, re, csr);

  // layer 1
  k_gemm1m<<<(N_NODES + 63) / 64, 256, 0, stream>>>(x, WT1, attl1, attr1, h1h, al1h, ar1);
  k_edge1<<<(N_NODES + 15) / 16, 256, 0, stream>>>(h1h, al1h, ar1, rs, re, csr, b1, y1h);

  // layer 2
  k_gemm2m<<<(N_NODES + 63) / 64, 256, 0, stream>>>(y1h, WT2, attl2, attr2, h2p, al2, ar2);
  k_edge2<<<(N_NODES + 31) / 32, 256, 0, stream>>>(h2p, al2, ar2, rs, re, csr, b2, out);
}

// Round 18
// 218.855 us; speedup vs baseline: 1.2494x; 1.0486x over previous
//
#include <hip/hip_runtime.h>
#include <math.h>

#define N_NODES 100000
#define N_EDGES 1600000
#define E2 (N_EDGES + N_NODES)
#define NEG_SLOPE 0.2f

#define NPB 128                      // nodes per bucket
#define NB  ((N_NODES + NPB - 1) / NPB)   // 782 buckets
#define CAP 2600                     // per-bucket raw edge capacity (mean ~2227, +8 sigma)
#define CAPP (CAP + 3 * NPB)         // padded capacity (2984)
#define BSLACK (3 * NPB + 4)         // per-bucket slack in final CSR (388)
#define BCH 4096                     // edges per block in k_bucket (LDS-cached)

typedef unsigned int uint;
typedef unsigned short ushort;
typedef __attribute__((ext_vector_type(2))) _Float16 h2_t;
typedef __attribute__((ext_vector_type(8))) _Float16 f16x8;
typedef __attribute__((ext_vector_type(4))) float f32x4;

union U8 { uint4 q; f16x8 v; h2_t h2[4]; _Float16 h[8]; uint u[4]; };

// ---------------- fp16 helpers ----------------

__device__ inline ushort f2h(float x) {
  _Float16 h = (_Float16)x;
  return *(ushort*)&h;
}

__device__ inline float h2f(ushort u) {
  _Float16 h = *(_Float16*)&u;
  return (float)h;
}

__device__ inline h2_t pk2h(float a, float b) {
  auto r = __builtin_amdgcn_cvt_pkrtz(a, b);   // __fp16 vec2 -> bit-cast
  return *(h2_t*)&r;
}

__device__ inline float fdot2(h2_t a, h2_t b, float c) {
#if __has_builtin(__builtin_amdgcn_fdot2)
  return __builtin_amdgcn_fdot2(*(__fp16 __attribute__((ext_vector_type(2)))*)&a,
                                *(__fp16 __attribute__((ext_vector_type(2)))*)&b,
                                c, false);
#else
  return c + (float)a.x * (float)b.x + (float)a.y * (float)b.y;
#endif
}

// ---------------- prep: W transposes (fp16) + attl1 fp16 + bucket cursor init ----------------

__global__ __launch_bounds__(256) void k_prepW(const float* __restrict__ W1,
                                               const float* __restrict__ W2,
                                               const float* __restrict__ attl1,
                                               ushort* __restrict__ WT1,
                                               ushort* __restrict__ WT2,
                                               ushort* __restrict__ attl1h,
                                               int* __restrict__ bcursor) {
  int b = blockIdx.x, t = threadIdx.x;
  if (b == 0) {
    for (int i = t; i < 128 * 128; i += 256) {
      int k = i >> 7, n = i & 127;
      WT1[n * 128 + k] = f2h(W1[i]);           // WT1[n][k]
    }
  } else if (b == 1) {
    for (int i = t; i < 48 * 128; i += 256) {
      int n = i >> 7, k = i & 127;
      WT2[i] = (n < 40) ? f2h(W2[k * 40 + n]) : (ushort)0;   // WT2[n][k], zero-pad n>=40
    }
    if (t < 128) attl1h[t] = f2h(attl1[t]);    // flattened [8][16]
  } else {
    for (int i = t; i < NB; i += 256) bcursor[i] = i * CAP;
  }
}

// ---------------- bucketed CSR construction (single global pass, LDS edge cache) ----------------

__global__ __launch_bounds__(256) void k_bucket(const int* __restrict__ ei,
                                                int* __restrict__ bcursor,
                                                uint* __restrict__ pbuf) {
  __shared__ uint pay[BCH];
  __shared__ ushort bkt[BCH];
  __shared__ int cnt[NB];
  __shared__ int base[NB];
  const int tid = threadIdx.x;
  const int ebase = blockIdx.x * BCH;
  for (int t = tid; t < NB; t += 256) cnt[t] = 0;
  __syncthreads();
#pragma unroll 4
  for (int k = 0; k < BCH / 256; ++k) {
    int idx = tid + k * 256;
    int e = ebase + idx;
    if (e < E2) {
      int s, d;
      if (e < N_EDGES) { s = ei[e]; d = ei[N_EDGES + e]; }
      else { s = e - N_EDGES; d = s; }
      pay[idx] = ((uint)s << 7) | (uint)(d & 127);
      int b = d >> 7;
      bkt[idx] = (ushort)b;
      atomicAdd(&cnt[b], 1);
    } else {
      bkt[idx] = 0xFFFFu;
    }
  }
  __syncthreads();
  for (int t = tid; t < NB; t += 256) {
    int c = cnt[t];
    base[t] = c ? atomicAdd(&bcursor[t], c) : 0;
    cnt[t] = 0;
  }
  __syncthreads();
#pragma unroll 4
  for (int k = 0; k < BCH / 256; ++k) {
    int idx = tid + k * 256;
    ushort b = bkt[idx];
    if (b != 0xFFFFu) {
      int pos = base[b] + atomicAdd(&cnt[b], 1);
      pbuf[pos] = pay[idx];
    }
  }
}

__global__ __launch_bounds__(1024) void k_scanB(const int* __restrict__ bcursor,
                                                int* __restrict__ bbase) {
  __shared__ int sm[1024];
  int t = threadIdx.x;
  int v = (t < NB) ? (bcursor[t] - t * CAP) : 0;
  sm[t] = v;
  __syncthreads();
  for (int off = 1; off < 1024; off <<= 1) {
    int u = (t >= off) ? sm[t - off] : 0;
    __syncthreads();
    sm[t] += u;
    __syncthreads();
  }
  if (t < NB) {
    int excl = sm[t] - v;
    bbase[t] = ((excl + 3) & ~3) + t * BSLACK;   // 16B-aligned start + per-bucket pad slack
  }
}

// Pass B: per-bucket CSR, per-node pad to multiple of 4 (sentinel = N_NODES). 128 threads/block.
__global__ __launch_bounds__(128) void k_csr(const uint* __restrict__ pbuf,
                                             const int* __restrict__ bcursor,
                                             const int* __restrict__ bbase,
                                             int* __restrict__ rs,
                                             int* __restrict__ re,
                                             int* __restrict__ csr) {
  __shared__ int hist[NPB];
  __shared__ int excl[NPB];
  __shared__ int cur[NPB];
  __shared__ int lcsr[CAPP];
  const int b = blockIdx.x;
  const int tid = threadIdx.x;
  int count = bcursor[b] - b * CAP;
  if (count > CAP) count = CAP;
  const int gbase = bbase[b];
  const uint* seg = pbuf + b * CAP;
  hist[tid] = 0;
  __syncthreads();
  for (int k = tid; k < count; k += 128) atomicAdd(&hist[seg[k] & 127u], 1);
  __syncthreads();
  int rounded = (hist[tid] + 3) & ~3;          // pad each node to multiple of 4
  excl[tid] = rounded;
  __syncthreads();
  for (int off = 1; off < 128; off <<= 1) {
    int u = (tid >= off) ? excl[tid - off] : 0;
    __syncthreads();
    excl[tid] += u;
    __syncthreads();
  }
  int ex = excl[tid] - rounded;
  cur[tid] = ex;
  int node = b * NPB + tid;
  if (node < N_NODES) {
    rs[node] = gbase + ex;
    re[node] = gbase + ex + rounded;
  }
  __syncthreads();
  const int ptotal = excl[NPB - 1];
  for (int k = tid; k < ptotal; k += 128) lcsr[k] = N_NODES;   // sentinel fill
  __syncthreads();
  for (int k = tid; k < count; k += 128) {
    uint pk = seg[k];
    int nd = pk & 127u;
    int pos = atomicAdd(&cur[nd], 1);
    lcsr[pos] = (int)(pk >> 7);
  }
  __syncthreads();
  for (int k = tid; k < ptotal; k += 128) csr[gbase + k] = lcsr[k];
}

// ---------------- GEMM 1 (MFMA f16) + fused ar1 + sentinel init ----------------

__global__ __launch_bounds__(256) void k_gemm1m(const float* __restrict__ x,
                                                const ushort* __restrict__ WT1,
                                                const float* __restrict__ attr,
                                                ushort* __restrict__ h1h,
                                                float* __restrict__ ar1) {
  __shared__ ushort stg[4][16][136];   // pad 128->136 (17 uint4/row)
  __shared__ h2_t attr_sm[64];
  const int tid = threadIdx.x;
  const int w = tid >> 6, l = tid & 63;
  const int r16 = l & 15, kq = l >> 4;
  const int rowbase = blockIdx.x * 64 + w * 16;
  if (tid < 64) attr_sm[tid] = pk2h(attr[2 * tid], attr[2 * tid + 1]);
  if (blockIdx.x == 0) {   // sentinel row N_NODES: h=0 (edge1 zeroes ex via explicit check)
    if (tid >= 128 && tid < 144) ((uint4*)h1h)[(size_t)N_NODES * 16 + (tid - 128)] = make_uint4(0, 0, 0, 0);
  }
  int arow = rowbase + r16;
  if (arow > N_NODES - 1) arow = N_NODES - 1;
  f16x8 af[4];
  const float* xr = x + (size_t)arow * 128 + kq * 8;
#pragma unroll
  for (int t = 0; t < 4; ++t) {
    float4 a0 = *(const float4*)(xr + t * 32);
    float4 a1 = *(const float4*)(xr + t * 32 + 4);
    U8 u;
    u.h2[0] = pk2h(a0.x, a0.y); u.h2[1] = pk2h(a0.z, a0.w);
    u.h2[2] = pk2h(a1.x, a1.y); u.h2[3] = pk2h(a1.z, a1.w);
    af[t] = u.v;
  }
  f32x4 acc[8];
#pragma unroll
  for (int n = 0; n < 8; ++n) acc[n] = (f32x4){0.f, 0.f, 0.f, 0.f};
  const uint4* WT4 = (const uint4*)WT1;   // row = 16 uint4 (128 fp16)
#pragma unroll
  for (int t = 0; t < 4; ++t) {
#pragma unroll
    for (int n = 0; n < 8; ++n) {
      U8 b;
      b.q = WT4[(size_t)(n * 16 + r16) * 16 + t * 4 + kq];
      acc[n] = __builtin_amdgcn_mfma_f32_16x16x32_f16(af[t], b.v, acc[n], 0, 0, 0);
    }
  }
#pragma unroll
  for (int n = 0; n < 8; ++n) {
#pragma unroll
    for (int r = 0; r < 4; ++r) stg[w][kq * 4 + r][n * 16 + r16] = f2h(acc[n][r]);
  }
  __syncthreads();
  uint4* H1 = (uint4*)h1h;
  const uint4* S = (const uint4*)stg[w];   // row stride 17 uint4
#pragma unroll
  for (int q = 0; q < 4; ++q) {
    int idx = l + q * 64;
    int row = idx >> 4, c4 = idx & 15;
    int grow = rowbase + row;
    if (grow < N_NODES) H1[(size_t)grow * 16 + c4] = S[row * 17 + c4];
  }
  // fused ar1: 128 (row,head) pairs per wave, 2 per lane
#pragma unroll
  for (int p = 0; p < 2; ++p) {
    int pidx = l + p * 64;
    int row = pidx >> 3, h = pidx & 7;
    int grow = rowbase + row;
    U8 a0, a1;
    a0.q = S[row * 17 + h * 2];
    a1.q = S[row * 17 + h * 2 + 1];
    float sr = 0.f;
#pragma unroll
    for (int k = 0; k < 4; ++k) {
      sr = fdot2(a0.h2[k], attr_sm[h * 8 + k], sr);
      sr = fdot2(a1.h2[k], attr_sm[h * 8 + 4 + k], sr);
    }
    if (grow < N_NODES) ar1[(size_t)grow * 8 + h] = sr;
  }
}

// ---------------- edge pass, layer 1: node per 16-lane group; al computed on the fly ----------------

__global__ __launch_bounds__(256) void k_edge1(const ushort* __restrict__ h1h,
                                               const ushort* __restrict__ attl1h,
                                               const float* __restrict__ ar1,
                                               const int* __restrict__ rs,
                                               const int* __restrict__ re,
                                               const int* __restrict__ csr,
                                               const float* __restrict__ b1,
                                               ushort* __restrict__ y1h) {
  const int tid = threadIdx.x;
  const int lane = tid & 63;
  const int wv = tid >> 6;
  const int grp = lane >> 4;
  const int l = lane & 15;
  const int h = l >> 1;
  const int node0 = (blockIdx.x * 4 + wv) * 4 + grp;
  const bool alive = node0 < N_NODES;
  const int i = alive ? node0 : N_NODES - 1;
  const int start = rs[i], end = re[i];
  const char* Hb = (const char*)h1h;
  const char* Cb = (const char*)csr;
  const uint loff = (uint)l * 16u;
  U8 uhi, au;
  uhi.q = *(const uint4*)(Hb + (uint)i * 256u + loff);
  au.q = *(const uint4*)(attl1h + l * 8);       // att_l slice for this lane's 8 channels
  const float ar_i = ar1[i * 8 + h];
  float s = 0.f;
  f16x8 acc = {};
  int4 ja = *(const int4*)(Cb + (uint)start * 4u);
  for (int e = start; e < end; e += 4) {
    int ep = (e + 4 < end) ? e + 4 : e;
    int4 jn = *(const int4*)(Cb + (uint)ep * 4u);
    U8 u0, u1, u2, u3;
    u0.q = *(const uint4*)(Hb + (uint)ja.x * 256u + loff);
    u1.q = *(const uint4*)(Hb + (uint)ja.y * 256u + loff);
    u2.q = *(const uint4*)(Hb + (uint)ja.z * 256u + loff);
    u3.q = *(const uint4*)(Hb + (uint)ja.w * 256u + loff);
    float p0 = 0.f, p1 = 0.f, p2 = 0.f, p3 = 0.f;
    float q0 = 0.f, q1 = 0.f, q2 = 0.f, q3 = 0.f;
#pragma unroll
    for (int k = 0; k < 4; ++k) {
      p0 = fdot2(uhi.h2[k], u0.h2[k], p0);
      p1 = fdot2(uhi.h2[k], u1.h2[k], p1);
      p2 = fdot2(uhi.h2[k], u2.h2[k], p2);
      p3 = fdot2(uhi.h2[k], u3.h2[k], p3);
      q0 = fdot2(au.h2[k], u0.h2[k], q0);
      q1 = fdot2(au.h2[k], u1.h2[k], q1);
      q2 = fdot2(au.h2[k], u2.h2[k], q2);
      q3 = fdot2(au.h2[k], u3.h2[k], q3);
    }
    p0 += __shfl_xor(p0, 1); q0 += __shfl_xor(q0, 1);
    p1 += __shfl_xor(p1, 1); q1 += __shfl_xor(q1, 1);
    p2 += __shfl_xor(p2, 1); q2 += __shfl_xor(q2, 1);
    p3 += __shfl_xor(p3, 1); q3 += __shfl_xor(q3, 1);
    float a0 = (q0 + ar_i) * (1.f / (1.f + __expf(-p0)));
    float a1 = (q1 + ar_i) * (1.f / (1.f + __expf(-p1)));
    float a2 = (q2 + ar_i) * (1.f / (1.f + __expf(-p2)));
    float a3 = (q3 + ar_i) * (1.f / (1.f + __expf(-p3)));
    a0 = fmaxf(a0, NEG_SLOPE * a0);
    a1 = fmaxf(a1, NEG_SLOPE * a1);
    a2 = fmaxf(a2, NEG_SLOPE * a2);
    a3 = fmaxf(a3, NEG_SLOPE * a3);
    float ex0 = (ja.x != N_NODES) ? __expf(a0) : 0.f;   // sentinel suppressed explicitly
    float ex1 = (ja.y != N_NODES) ? __expf(a1) : 0.f;
    float ex2 = (ja.z != N_NODES) ? __expf(a2) : 0.f;
    float ex3 = (ja.w != N_NODES) ? __expf(a3) : 0.f;
    s += (ex0 + ex1) + (ex2 + ex3);
    acc += u0.v * (_Float16)ex0;
    acc += u1.v * (_Float16)ex1;
    acc += u2.v * (_Float16)ex2;
    acc += u3.v * (_Float16)ex3;
    ja = jn;
  }
  float inv = 1.f / s;
  float4 bb0 = *(const float4*)(b1 + l * 8);
  float4 bb1 = *(const float4*)(b1 + l * 8 + 4);
  float o[8];
#pragma unroll
  for (int c = 0; c < 8; ++c) {
    float b = (c < 4) ? ((const float*)&bb0)[c] : ((const float*)&bb1)[c - 4];
    float v = (float)acc[c] * inv + b;
    o[c] = v > 0.f ? v : __expf(v) - 1.f;       // ELU
  }
  if (alive) {
    U8 pk;
#pragma unroll
    for (int c = 0; c < 4; ++c) pk.h2[c] = pk2h(o[2 * c], o[2 * c + 1]);
    ((uint4*)y1h)[(size_t)i * 16 + l] = pk.q;
  }
}

// ---------------- GEMM 2 (MFMA f16) + fused alr2; rows = 6 uint4 (40ch + embedded al, bf16-safe) ----------------

__global__ __launch_bounds__(256) void k_gemm2m(const ushort* __restrict__ y1h,
                                                const ushort* __restrict__ WT2,
                                                const float* __restrict__ attl,
                                                const float* __restrict__ attr,
                                                ushort* __restrict__ h2p,
                                                float* __restrict__ ar2) {
  __shared__ ushort stg[4][16][56];    // pad 48->56 (7 uint4/row)
  __shared__ h2_t attl_sm[20], attr_sm[20];
  const int tid = threadIdx.x;
  const int w = tid >> 6, l = tid & 63;
  const int r16 = l & 15, kq = l >> 4;
  const int rowbase = blockIdx.x * 64 + w * 16;
  if (tid < 20) attl_sm[tid] = pk2h(attl[2 * tid], attl[2 * tid + 1]);
  else if (tid >= 32 && tid < 52) { int t = tid - 32; attr_sm[t] = pk2h(attr[2 * t], attr[2 * t + 1]); }
  if (blockIdx.x == 0) {   // sentinel row: h2=0, embedded al=-1e30 with low 16 bits cleared
    if (tid >= 64 && tid < 70) {
      int c = tid - 64;
      uint4 v = make_uint4(0, 0, 0, 0);
      if (c == 5) v.x = __float_as_uint(-1e30f) & 0xFFFF0000u;
      ((uint4*)h2p)[(size_t)N_NODES * 6 + c] = v;
    }
  }
  int arow = rowbase + r16;
  if (arow > N_NODES - 1) arow = N_NODES - 1;
  const uint4* Y4 = (const uint4*)y1h;   // row = 16 uint4
  f16x8 af[4];
#pragma unroll
  for (int t = 0; t < 4; ++t) {
    U8 u;
    u.q = Y4[(size_t)arow * 16 + t * 4 + kq];
    af[t] = u.v;
  }
  f32x4 acc[3];
#pragma unroll
  for (int n = 0; n < 3; ++n) acc[n] = (f32x4){0.f, 0.f, 0.f, 0.f};
  const uint4* WT4 = (const uint4*)WT2;   // 48 rows x 16 uint4
#pragma unroll
  for (int t = 0; t < 4; ++t) {
#pragma unroll
    for (int n = 0; n < 3; ++n) {
      U8 b;
      b.q = WT4[(size_t)(n * 16 + r16) * 16 + t * 4 + kq];
      acc[n] = __builtin_amdgcn_mfma_f32_16x16x32_f16(af[t], b.v, acc[n], 0, 0, 0);
    }
  }
#pragma unroll
  for (int n = 0; n < 3; ++n) {
#pragma unroll
    for (int r = 0; r < 4; ++r) stg[w][kq * 4 + r][n * 16 + r16] = f2h(acc[n][r]);
  }
  __syncthreads();
  uint4* H2 = (uint4*)h2p;               // row = 6 uint4 (96B)
  const uint4* S = (const uint4*)stg[w]; // row stride 7 uint4
#pragma unroll
  for (int q = 0; q < 2; ++q) {
    int idx = l + q * 64;                // 0..127; active < 80
    if (idx < 80) {
      int row = idx / 5, c4 = idx % 5;
      int grow = rowbase + row;
      if (grow < N_NODES) H2[(size_t)grow * 6 + c4] = S[row * 7 + c4];
    }
  }
  // fused alr2: 16 rows x {al, ar}; al embedded in row word 5 with low 16 bits cleared
  // (fp16 reinterpretation of the stored word must never be NaN: low half = +0, high half finite)
  if (l < 32) {
    int row = l & 15, sel = l >> 4;
    int grow = rowbase + row;
    const h2_t* att = sel ? attr_sm : attl_sm;
    float v = 0.f;
#pragma unroll
    for (int q = 0; q < 5; ++q) {
      U8 b;
      b.q = S[row * 7 + q];
#pragma unroll
      for (int k = 0; k < 4; ++k) v = fdot2(b.h2[k], att[q * 4 + k], v);
    }
    if (grow < N_NODES) {
      if (sel) ar2[grow] = v;
      else     H2[(size_t)grow * 6 + 5] = make_uint4(__float_as_uint(v) & 0xFFFF0000u, 0, 0, 0);
    }
  }
}

// ---------------- edge pass, layer 2: node per 8-lane group; al rides with row gather ----------------

__global__ __launch_bounds__(256) void k_edge2(const ushort* __restrict__ h2p,
                                               const float* __restrict__ ar2,
                                               const int* __restrict__ rs,
                                               const int* __restrict__ re,
                                               const int* __restrict__ csr,
                                               const float* __restrict__ b2,
                                               float* __restrict__ out) {
  const int tid = threadIdx.x;
  const int lane = tid & 63;
  const int wv = tid >> 6;
  const int grp = lane >> 3;
  const int l = lane & 7;
  const int node0 = (blockIdx.x * 4 + wv) * 8 + grp;
  const bool alive = node0 < N_NODES;
  const int i = alive ? node0 : N_NODES - 1;
  const int start = rs[i], end = re[i];
  const char* Hb = (const char*)h2p;
  const char* Cb = (const char*)csr;
  const uint loff = (uint)(l <= 5 ? l : 0) * 16u;  // lane 5 picks up the embedded al word
  const int srcl = (lane & 56) | 5;                // group's lane 5 (for al broadcast)
  U8 uhi;
  uhi.q = *(const uint4*)(Hb + (uint)i * 96u + loff);
  if (l >= 5) uhi.q = make_uint4(0, 0, 0, 0);      // mask -> dot contributions are 0
  const float ar_i = ar2[i];
  float s = 0.f;
  f16x8 acc = {};
  int4 ja = *(const int4*)(Cb + (uint)start * 4u);
  for (int e = start; e < end; e += 4) {
    int ep = (e + 4 < end) ? e + 4 : e;
    int4 jn = *(const int4*)(Cb + (uint)ep * 4u);
    U8 u0, u1, u2, u3;
    u0.q = *(const uint4*)(Hb + (uint)ja.x * 96u + loff);
    u1.q = *(const uint4*)(Hb + (uint)ja.y * 96u + loff);
    u2.q = *(const uint4*)(Hb + (uint)ja.z * 96u + loff);
    u3.q = *(const uint4*)(Hb + (uint)ja.w * 96u + loff);
    // broadcast embedded al (bf16-truncated fp32 in lane 5's word 0) to the group
    float av0 = __uint_as_float((uint)__shfl((int)u0.u[0], srcl));
    float av1 = __uint_as_float((uint)__shfl((int)u1.u[0], srcl));
    float av2 = __uint_as_float((uint)__shfl((int)u2.u[0], srcl));
    float av3 = __uint_as_float((uint)__shfl((int)u3.u[0], srcl));
    float p0 = 0.f, p1 = 0.f, p2 = 0.f, p3 = 0.f;
#pragma unroll
    for (int k = 0; k < 4; ++k) {
      p0 = fdot2(uhi.h2[k], u0.h2[k], p0);
      p1 = fdot2(uhi.h2[k], u1.h2[k], p1);
      p2 = fdot2(uhi.h2[k], u2.h2[k], p2);
      p3 = fdot2(uhi.h2[k], u3.h2[k], p3);
    }
#pragma unroll
    for (int m = 1; m <= 4; m <<= 1) {
      p0 += __shfl_xor(p0, m);
      p1 += __shfl_xor(p1, m);
      p2 += __shfl_xor(p2, m);
      p3 += __shfl_xor(p3, m);
    }
    float a0 = (av0 + ar_i) * (1.f / (1.f + __expf(-p0)));
    float a1 = (av1 + ar_i) * (1.f / (1.f + __expf(-p1)));
    float a2 = (av2 + ar_i) * (1.f / (1.f + __expf(-p2)));
    float a3 = (av3 + ar_i) * (1.f / (1.f + __expf(-p3)));
    a0 = fmaxf(a0, NEG_SLOPE * a0);
    a1 = fmaxf(a1, NEG_SLOPE * a1);
    a2 = fmaxf(a2, NEG_SLOPE * a2);
    a3 = fmaxf(a3, NEG_SLOPE * a3);
    float ex0 = __expf(a0);   // sentinel: al=-1e30, p=0 -> a=-2e29 -> ex=0 exactly
    float ex1 = __expf(a1);
    float ex2 = __expf(a2);
    float ex3 = __expf(a3);
    s += (ex0 + ex1) + (ex2 + ex3);
    acc += u0.v * (_Float16)ex0;
    acc += u1.v * (_Float16)ex1;
    acc += u2.v * (_Float16)ex2;
    acc += u3.v * (_Float16)ex3;
    ja = jn;
  }
  // epilogue: bias + log_softmax over 40 classes (group-local)
  float inv = 1.f / s;
  bool act = l < 5;
  float o[8];
  float mx = -1e30f;
#pragma unroll
  for (int c = 0; c < 8; ++c) {
    float b = act ? b2[l * 8 + c] : 0.f;
    o[c] = (float)acc[c] * inv + b;
    if (act) mx = fmaxf(mx, o[c]);
  }
  mx = fmaxf(mx, __shfl_xor(mx, 1));
  mx = fmaxf(mx, __shfl_xor(mx, 2));
  mx = fmaxf(mx, __shfl_xor(mx, 4));
  float se = 0.f;
  if (act) {
#pragma unroll
    for (int c = 0; c < 8; ++c) se += __expf(o[c] - mx);
  }
  se += __shfl_xor(se, 1);
  se += __shfl_xor(se, 2);
  se += __shfl_xor(se, 4);
  if (alive && act) {
    float lse = mx + __logf(se);
    float4 r0 = make_float4(o[0] - lse, o[1] - lse, o[2] - lse, o[3] - lse);
    float4 r1 = make_float4(o[4] - lse, o[5] - lse, o[6] - lse, o[7] - lse);
    float4* O = (float4*)(out + (size_t)i * 40 + l * 8);
    O[0] = r0;
    O[1] = r1;
  }
}

// ---------------- launcher ----------------

extern "C" void kernel_launch(void* const* d_in, const int* in_sizes, int n_in,
                              void* d_out, int out_size, void* d_ws, size_t ws_size,
                              hipStream_t stream) {
  const float* x     = (const float*)d_in[0];
  const int*   ei    = (const int*)d_in[1];
  const float* W1    = (const float*)d_in[2];
  const float* attl1 = (const float*)d_in[3];
  const float* attr1 = (const float*)d_in[4];
  const float* b1    = (const float*)d_in[5];
  const float* W2    = (const float*)d_in[6];
  const float* attl2 = (const float*)d_in[7];
  const float* attr2 = (const float*)d_in[8];
  const float* b2    = (const float*)d_in[9];
  float* out = (float*)d_out;

  char* wsp = (char*)d_ws;
  size_t off = 0;
  auto alloc = [&](size_t bytes) {
    char* p = wsp + off;
    off = (off + bytes + 255) & ~(size_t)255;
    return p;
  };
  ushort* h1h   = (ushort*)alloc((size_t)(N_NODES + 1) * 128 * 2);  // fp16 h1 (+sentinel row)
  ushort* y1h   = (ushort*)alloc((size_t)N_NODES * 128 * 2);        // fp16 y1
  float* ar1    = (float*)alloc((size_t)N_NODES * 8 * 4);
  int* rs       = (int*)alloc((size_t)(N_NODES + 4) * 4);
  int* re       = (int*)alloc((size_t)(N_NODES + 4) * 4);
  int* bcursor  = (int*)alloc((size_t)NB * 4);
  int* bbase    = (int*)alloc((size_t)NB * 4);
  int* csr      = (int*)alloc((size_t)(E2 + NB * BSLACK + 16) * 4); // padded CSR
  ushort* WT1   = (ushort*)alloc(128 * 128 * 2);
  ushort* WT2   = (ushort*)alloc(48 * 128 * 2);
  ushort* attl1h = (ushort*)alloc(128 * 2);
  uint* pbuf  = (uint*)y1h;   // overlay: pbuf (8.1MB) dead before edge1 writes y1h
  ushort* h2p = h1h;          // reuse: h1h dead after edge1 ((N+1)*96B <= (N+1)*256B)
  float* ar2  = (float*)ar1;  // reuse: ar1 dead after edge1 (needs N floats <= N*8)

  // prep + CSR build
  k_prepW<<<3, 256, 0, stream>>>(W1, W2, attl1, WT1, WT2, attl1h, bcursor);
  k_bucket<<<(E2 + BCH - 1) / BCH, 256, 0, stream>>>(ei, bcursor, pbuf);
  k_scanB<<<1, 1024, 0, stream>>>(bcursor, bbase);
  k_csr<<<NB, 128, 0, stream>>>(pbuf, bcursor, bbase, rs, re, csr);

  // layer 1
  k_gemm1m<<<(N_NODES + 63) / 64, 256, 0, stream>>>(x, WT1, attr1, h1h, ar1);
  k_edge1<<<(N_NODES + 15) / 16, 256, 0, stream>>>(h1h, attl1h, ar1, rs, re, csr, b1, y1h);

  // layer 2
  k_gemm2m<<<(N_NODES + 63) / 64, 256, 0, stream>>>(y1h, WT2, attl2, attr2, h2p, ar2);
  k_edge2<<<(N_NODES + 31) / 32, 256, 0, stream>>>(h2p, ar2, rs, re, csr, b2, out);
}